// Round 6
// baseline (303.678 us; speedup 1.0000x reference)
//
#include <hip/hip_runtime.h>
#include <hip/hip_bf16.h>
#include <math.h>

// Problem constants (from reference)
#define DM   1024        // d_model
#define DI   2048        // d_inner
#define DS   16          // d_state
#define DTR  64          // dt_rank
#define NB   2           // batch
#define LL   1024        // seq len
#define MR   (NB*LL)     // 2048 rows (b*l flattened)
#define XDBL 96          // dt_rank + 2*d_state
#define NC   32          // scan chunks (CL=32 keeps 2 blocks/CU — R5 lesson)
#define CL   32          // chunk length

typedef _Float16 half8  __attribute__((ext_vector_type(8)));
typedef _Float16 half4v __attribute__((ext_vector_type(4)));
typedef float    floatx4 __attribute__((ext_vector_type(4)));

__device__ __forceinline__ void gload_lds16(const void* g, void* l) {
  __builtin_amdgcn_global_load_lds(
      (const __attribute__((address_space(1))) void*)g,
      (__attribute__((address_space(3))) void*)l, 16, 0, 0);
}

// ---------------------------------------------------------------------------
// K1 front: LN (blocks < MR) + weight f2h (next 6464) + A-table (last 8).
// A-table: a[s] = -exp(A_log), per-d fast flag (S4D init a[s] == -(s+1)) so
// scan kernels skip per-thread exp detection.
// ---------------------------------------------------------------------------
__global__ __launch_bounds__(256) void front_kernel(
    const float* __restrict__ x, const float* __restrict__ ln_w,
    const float* __restrict__ ln_b,
    const float* __restrict__ w_in, const float* __restrict__ w_out,
    const float* __restrict__ w_xp, const float* __restrict__ w_dt,
    const float* __restrict__ A_log,
    _Float16* __restrict__ h_h,
    _Float16* __restrict__ w_in_h, _Float16* __restrict__ w_out_h,
    _Float16* __restrict__ w_xp_h, _Float16* __restrict__ w_dt_h,
    float* __restrict__ atab, unsigned char* __restrict__ aflag) {
  const int blk = blockIdx.x;
  if (blk < MR) {
    __shared__ float sA[4], sB[4];
    const float* xr = x + (size_t)blk * DM;
    float s = 0.f, ss = 0.f;
    for (int i = threadIdx.x; i < DM; i += 256) {
      float v = xr[i];
      s += v; ss += v * v;
    }
    for (int o = 32; o > 0; o >>= 1) {
      s  += __shfl_down(s, o, 64);
      ss += __shfl_down(ss, o, 64);
    }
    const int wid = threadIdx.x >> 6, lid = threadIdx.x & 63;
    if (lid == 0) { sA[wid] = s; sB[wid] = ss; }
    __syncthreads();
    if (threadIdx.x == 0) {
      float S = sA[0] + sA[1] + sA[2] + sA[3];
      float SS = sB[0] + sB[1] + sB[2] + sB[3];
      float mu = S / DM;
      sA[0] = mu;
      sB[0] = rsqrtf(SS / DM - mu * mu + 1e-5f);
    }
    __syncthreads();
    const float mu = sA[0], rs = sB[0];
    for (int i = threadIdx.x; i < DM; i += 256)
      h_h[(size_t)blk * DM + i] = (_Float16)((xr[i] - mu) * rs * ln_w[i] + ln_b[i]);
    return;
  }
  if (blk >= MR + 6464) {                         // A-table blocks (8)
    const int d = (blk - (MR + 6464)) * 256 + threadIdx.x;
    if (d < DI) {
      bool fast = true;
      float a[DS];
#pragma unroll
      for (int s = 0; s < DS; s++) {
        a[s] = -__expf(A_log[(size_t)d * DS + s]);
        atab[(size_t)d * DS + s] = a[s];
        fast = fast && (fabsf(a[s] + (float)(s + 1)) < 1e-4f);
      }
      aflag[d] = fast ? 1 : 0;
    }
    return;
  }
  int i = (blk - MR) * 256 + threadIdx.x;
  const int N0 = 1048576, N1 = 524288, N2 = 49152, N3 = 32768;
  const float* s; _Float16* d; int off;
  if (i < N0)            { s = w_in;  d = w_in_h;  off = i; }
  else if (i < N0+N1)    { s = w_out; d = w_out_h; off = i - N0; }
  else if (i < N0+N1+N2) { s = w_xp;  d = w_xp_h;  off = i - N0 - N1; }
  else if (i < N0+N1+N2+N3) { s = w_dt; d = w_dt_h; off = i - N0 - N1 - N2; }
  else return;
  float4 v = ((const float4*)s)[off];
  half4v h = {(_Float16)v.x, (_Float16)v.y, (_Float16)v.z, (_Float16)v.w};
  ((half4v*)d)[off] = h;
}

// ---------------------------------------------------------------------------
// MFMA f16 GEMM — verified counted-vmcnt depth-3 pipeline (R13). Tile 128xTN.
// EPI 0: dual f16 store (n<DI -> Cv else C2v, compact DI-wide rows)
// EPI 7: f32 store out = x + acc (single-pass full-K; C2v = x)
// ---------------------------------------------------------------------------
template <int EPI, int TN>
__global__ __launch_bounds__(256) void gemm_mfma(
    const _Float16* __restrict__ A,   // [M][K]
    const _Float16* __restrict__ W,   // [N][K]
    void* __restrict__ Cv, void* __restrict__ C2v, int ldc,
    int M, int N, int K, int kchunk) {
  constexpr int NT = (TN + 31) / 32;
  constexpr int WSLOT = TN / 16;
  constexpr int LPS = 2 + (WSLOT >= 8 ? 2 : 1);
  __shared__ alignas(16) _Float16 As[4][4096];
  __shared__ alignas(16) _Float16 Ws[4][4096];
  const int t = threadIdx.x;
  const int wave = t >> 6, lane = t & 63;
  const int m0 = blockIdx.y * 128, n0 = blockIdx.x * TN;
  const int k_beg = blockIdx.z * kchunk;
  const int nk = kchunk / 32;
  const int wm = (wave >> 1) * 64, wn = (wave & 1) * (TN / 2);
  floatx4 acc[4][NT];
#pragma unroll
  for (int i = 0; i < 4; i++)
#pragma unroll
    for (int j = 0; j < NT; j++) acc[i][j] = {0.f, 0.f, 0.f, 0.f};

  const int fr = lane & 15;
  const int kc8 = lane >> 4;
  const int kp = (kc8 ^ ((fr >> 1) & 3)) * 8;   // XOR bank swizzle

  auto stage = [&](int buf, int k0) {
    for (int sl = wave; sl < 8; sl += 4) {
      const int idx = sl * 64 + lane;
      const int row = idx >> 2;
      const int kc = (idx & 3) ^ ((row >> 1) & 3);
      gload_lds16(A + (size_t)(m0 + row) * K + k0 + kc * 8, &As[buf][sl * 512]);
    }
    for (int sl = wave; sl < WSLOT; sl += 4) {
      const int idx = sl * 64 + lane;
      const int row = idx >> 2;
      const int kc = (idx & 3) ^ ((row >> 1) & 3);
      const int wrow = (n0 + row < N) ? row : 0;
      gload_lds16(W + (size_t)(n0 + wrow) * K + k0 + kc * 8, &Ws[buf][sl * 512]);
    }
  };

  const int npre = nk < 3 ? nk : 3;
  for (int p = 0; p < npre; p++) stage(p, k_beg + p * 32);

  for (int ki = 0; ki < nk; ki++) {
    const int rem = nk - 1 - ki;
    if (rem >= 2)
      asm volatile("s_waitcnt vmcnt(%0)" :: "n"(2 * LPS) : "memory");
    else if (rem == 1)
      asm volatile("s_waitcnt vmcnt(%0)" :: "n"(LPS) : "memory");
    else
      asm volatile("s_waitcnt vmcnt(0)" ::: "memory");
    __builtin_amdgcn_s_barrier();
    const int cur = ki & 3;
    half8 af[4], wf[NT];
#pragma unroll
    for (int i = 0; i < 4; i++)
      af[i] = *(const half8*)&As[cur][(wm + i * 16 + fr) * 32 + kp];
#pragma unroll
    for (int j = 0; j < NT; j++)
      wf[j] = *(const half8*)&Ws[cur][(wn + j * 16 + fr) * 32 + kp];
    __builtin_amdgcn_s_setprio(1);
#pragma unroll
    for (int i = 0; i < 4; i++)
#pragma unroll
      for (int j = 0; j < NT; j++)
        acc[i][j] = __builtin_amdgcn_mfma_f32_16x16x32_f16(af[i], wf[j], acc[i][j], 0, 0, 0);
    __builtin_amdgcn_s_setprio(0);
    if (ki + 3 < nk) stage((ki + 3) & 3, k_beg + (ki + 3) * 32);
  }

  // epilogue: C/D layout col = lane&15, row = (lane>>4)*4 + reg
  const int col = lane & 15, rowq = lane >> 4;
#pragma unroll
  for (int i = 0; i < 4; i++) {
#pragma unroll
    for (int j = 0; j < NT; j++) {
      const int n = n0 + wn + j * 16 + col;
      if (n < N) {
#pragma unroll
        for (int r = 0; r < 4; r++) {
          const int m = m0 + wm + i * 16 + rowq * 4 + r;
          float v = acc[i][j][r];
          if (EPI == 0) {
            if (n < DI) ((_Float16*)Cv )[(size_t)m * DI + n]      = (_Float16)v;
            else        ((_Float16*)C2v)[(size_t)m * DI + n - DI] = (_Float16)v;
          } else if (EPI == 7) {
            ((float*)Cv)[(size_t)m * ldc + n] =
                ((const float*)C2v)[(size_t)m * ldc + n] + v;
          }
        }
      }
    }
  }
}

// ---------------------------------------------------------------------------
// K3 x_proj GEMM with INLINE CONV in the A-staging (conv kernel deleted).
// A-tile element = silu(conv_b + sum_k xin[m-3+k]*conv_w[k]) computed in regs
// then ds_write with the verified XOR layout (dt_kernel's staging pattern).
// K=128 per z-split (4 slabs staged upfront, 1 barrier). EPI: f16 partials.
// ---------------------------------------------------------------------------
__global__ __launch_bounds__(256) void xproj_conv(
    const _Float16* __restrict__ xin, const _Float16* __restrict__ W,
    const float* __restrict__ cw, const float* __restrict__ cb,
    _Float16* __restrict__ part) {      // [16][MR][96]
  __shared__ alignas(16) _Float16 As[4][4096];   // 4 slabs x 128x32
  __shared__ alignas(16) _Float16 Ws[4][3072];   // 4 slabs x 96x32
  const int t = threadIdx.x, wave = t >> 6, lane = t & 63;
  const int m0 = blockIdx.y * 128;
  const int k0 = blockIdx.z * 128;
  // A staging with inline conv: 4 slabs x 512 half8.
  for (int q = t; q < 2048; q += 256) {
    const int ss = q >> 9, idx = q & 511;
    const int row = idx >> 2;
    const int kc = (idx & 3) ^ ((row >> 1) & 3);
    const int m = m0 + row;
    const int l = m & (LL - 1);
    const int dbase = k0 + ss * 32 + kc * 8;
    float accv[8];
#pragma unroll
    for (int j = 0; j < 8; j++) accv[j] = cb[dbase + j];
#pragma unroll
    for (int k = 0; k < 4; k++) {
      const int lp = l - 3 + k;
      if (lp >= 0) {
        half8 xv = *(const half8*)&xin[(size_t)(m - 3 + k) * DI + dbase];
#pragma unroll
        for (int j = 0; j < 8; j++)
          accv[j] += (float)xv[j] * cw[(dbase + j) * 4 + k];
      }
    }
    half8 o;
#pragma unroll
    for (int j = 0; j < 8; j++)
      o[j] = (_Float16)(accv[j] / (1.f + __expf(-accv[j])));
    *(half8*)&As[ss][idx * 8] = o;
  }
  // W staging: 4 slabs x 6 slots via gload_lds16
  for (int q = wave; q < 24; q += 4) {
    const int ss = q / 6, sw = q % 6;
    const int idx = sw * 64 + lane;
    const int row = idx >> 2;
    const int kc = (idx & 3) ^ ((row >> 1) & 3);
    gload_lds16(W + (size_t)row * DI + k0 + ss * 32 + kc * 8, &Ws[ss][sw * 512]);
  }
  asm volatile("s_waitcnt vmcnt(0)" ::: "memory");
  __syncthreads();
  const int fr = lane & 15, kc8 = lane >> 4;
  const int kp = (kc8 ^ ((fr >> 1) & 3)) * 8;
  const int wm = (wave >> 1) * 64, wn = (wave & 1) * 48;
  floatx4 acc[4][3];
#pragma unroll
  for (int i = 0; i < 4; i++)
#pragma unroll
    for (int j = 0; j < 3; j++) acc[i][j] = {0.f, 0.f, 0.f, 0.f};
#pragma unroll
  for (int ss = 0; ss < 4; ss++) {
    half8 af[4], wf[3];
#pragma unroll
    for (int i = 0; i < 4; i++)
      af[i] = *(const half8*)&As[ss][(wm + i * 16 + fr) * 32 + kp];
#pragma unroll
    for (int j = 0; j < 3; j++)
      wf[j] = *(const half8*)&Ws[ss][(wn + j * 16 + fr) * 32 + kp];
#pragma unroll
    for (int i = 0; i < 4; i++)
#pragma unroll
      for (int j = 0; j < 3; j++)
        acc[i][j] = __builtin_amdgcn_mfma_f32_16x16x32_f16(af[i], wf[j], acc[i][j], 0, 0, 0);
  }
  const int col = lane & 15, rowq = lane >> 4;
#pragma unroll
  for (int i = 0; i < 4; i++) {
#pragma unroll
    for (int j = 0; j < 3; j++) {
      const int n = wn + j * 16 + col;
#pragma unroll
      for (int r = 0; r < 4; r++) {
        const int m = m0 + wm + i * 16 + rowq * 4 + r;
        part[((size_t)blockIdx.z * MR + m) * XDBL + n] = (_Float16)acc[i][j][r];
      }
    }
  }
}

// ---------------------------------------------------------------------------
// K4 dt GEMM: A = sum of 16 f16 partials (cols 0..63) staged in-register
// (xproj_reduce deleted). Tile 128x64, K=64 (2 slabs), one barrier.
// Epilogue: softplus(acc + bias[n]) -> f16 dtb.
// ---------------------------------------------------------------------------
__global__ __launch_bounds__(256) void dt_kernel(
    const _Float16* __restrict__ part, const _Float16* __restrict__ W,
    const float* __restrict__ bias, _Float16* __restrict__ dtb) {
  __shared__ alignas(16) _Float16 As[2][4096];   // 2 slabs x 128x32
  __shared__ alignas(16) _Float16 Ws[2][2048];   // 2 slabs x 64x32
  const int t = threadIdx.x, wave = t >> 6, lane = t & 63;
  const int m0 = blockIdx.y * 128, n0 = blockIdx.x * 64;
  for (int q = wave; q < 16; q += 4) {           // A: 2 slabs x 8 slots
    const int ss = q >> 3, sl = q & 7;
    const int idx = sl * 64 + lane;
    const int row = idx >> 2;
    const int kc = (idx & 3) ^ ((row >> 1) & 3);
    const int cbase = ss * 32 + kc * 8;          // dt cols < 64
    float a8[8] = {0.f, 0.f, 0.f, 0.f, 0.f, 0.f, 0.f, 0.f};
#pragma unroll
    for (int z = 0; z < 16; z++) {
      half8 p = *(const half8*)&part[((size_t)z * MR + m0 + row) * XDBL + cbase];
#pragma unroll
      for (int j = 0; j < 8; j++) a8[j] += (float)p[j];
    }
    half8 h = {(_Float16)a8[0], (_Float16)a8[1], (_Float16)a8[2], (_Float16)a8[3],
               (_Float16)a8[4], (_Float16)a8[5], (_Float16)a8[6], (_Float16)a8[7]};
    *(half8*)&As[ss][idx * 8] = h;
  }
  for (int q = wave; q < 8; q += 4) {            // W: 2 slabs x 4 slots
    const int ss = q >> 2, sw = q & 3;
    const int idx = sw * 64 + lane;
    const int row = idx >> 2;
    const int kc = (idx & 3) ^ ((row >> 1) & 3);
    gload_lds16(W + (size_t)(n0 + row) * DTR + ss * 32 + kc * 8,
                &Ws[ss][sw * 512]);
  }
  asm volatile("s_waitcnt vmcnt(0)" ::: "memory");
  __syncthreads();
  const int fr = lane & 15, kc8 = lane >> 4;
  const int kp = (kc8 ^ ((fr >> 1) & 3)) * 8;
  const int wm = (wave >> 1) * 64, wn = (wave & 1) * 32;
  floatx4 acc[4][2];
#pragma unroll
  for (int i = 0; i < 4; i++)
#pragma unroll
    for (int j = 0; j < 2; j++) acc[i][j] = {0.f, 0.f, 0.f, 0.f};
#pragma unroll
  for (int ss = 0; ss < 2; ss++) {
    half8 af[4], wf[2];
#pragma unroll
    for (int i = 0; i < 4; i++)
      af[i] = *(const half8*)&As[ss][(wm + i * 16 + fr) * 32 + kp];
#pragma unroll
    for (int j = 0; j < 2; j++)
      wf[j] = *(const half8*)&Ws[ss][(wn + j * 16 + fr) * 32 + kp];
#pragma unroll
    for (int i = 0; i < 4; i++)
#pragma unroll
      for (int j = 0; j < 2; j++)
        acc[i][j] = __builtin_amdgcn_mfma_f32_16x16x32_f16(af[i], wf[j], acc[i][j], 0, 0, 0);
  }
  const int col = lane & 15, rowq = lane >> 4;
#pragma unroll
  for (int i = 0; i < 4; i++) {
#pragma unroll
    for (int j = 0; j < 2; j++) {
      const int n = n0 + wn + j * 16 + col;
#pragma unroll
      for (int r = 0; r < 4; r++) {
        const int m = m0 + wm + i * 16 + rowq * 4 + r;
        float v = acc[i][j][r] + bias[n];
        v = (v > 20.f) ? v : __logf(1.f + __expf(v));
        dtb[(size_t)m * DI + n] = (_Float16)v;
      }
    }
  }
}

// ---------------------------------------------------------------------------
// K5 scan phase 1: inline conv (rolling window over xin), B/C summed from
// partials into LDS. Emits HE (chunk-local end state), SA (sum dt), and NEW:
// pl = p_local + u*D (f16), cd = cumulative dt (f16, ALIASES dtb — each
// (ml,d) is read-then-overwritten by its owning thread; store value depends
// on the load so no reorder hazard).
// ---------------------------------------------------------------------------
__global__ __launch_bounds__(256) void scan_p1(
    const _Float16* __restrict__ xin, const _Float16* __restrict__ part,
    const _Float16* dtb,
    const float* __restrict__ atab, const unsigned char* __restrict__ aflag,
    const float* __restrict__ cw, const float* __restrict__ cb,
    const float* __restrict__ Dvec,
    float* __restrict__ HE, float* __restrict__ SA,
    _Float16* __restrict__ pl, _Float16* cd) {
  __shared__ float Bs[CL][DS];
  __shared__ float Cs[CL][DS];
  const int bi = blockIdx.x;
  const int dblk = bi & 7;
  const int c = (bi >> 3) & (NC - 1);
  const int b = bi >> 8;
  const int t = threadIdx.x;
  const int d = dblk * 256 + t;
  const int mlbase = b * LL + c * CL;

  for (int i = t; i < CL * DS; i += 256) {
    const int tt = i >> 4, s = i & 15;
    float sb = 0.f, sc = 0.f;
#pragma unroll
    for (int z = 0; z < 16; z++) {
      const size_t ro = ((size_t)z * MR + mlbase + tt) * XDBL;
      sb += (float)part[ro + DTR + s];
      sc += (float)part[ro + DTR + DS + s];
    }
    Bs[tt][s] = sb;
    Cs[tt][s] = sc;
  }

  const bool fast = aflag[d] != 0;
  float a[DS];
  if (!fast) {
#pragma unroll
    for (int s = 0; s < DS; s++) a[s] = atab[(size_t)d * DS + s];
  }
  float cw4[4];
#pragma unroll
  for (int k = 0; k < 4; k++) cw4[k] = cw[d * 4 + k];
  const float cbv = cb[d], Dv = Dvec[d];
  // conv window warmup (rows mlbase-3..mlbase-1; zero when l would be <0)
  float w0 = 0.f, w1 = 0.f, w2 = 0.f;
  if (c > 0) {
    w0 = (float)xin[(size_t)(mlbase - 3) * DI + d];
    w1 = (float)xin[(size_t)(mlbase - 2) * DI + d];
    w2 = (float)xin[(size_t)(mlbase - 1) * DI + d];
  }
  float h[DS];
#pragma unroll
  for (int s = 0; s < DS; s++) h[s] = 0.f;
  float S = 0.f;
  __syncthreads();

  for (int tt = 0; tt < CL; tt++) {
    const size_t ml = mlbase + tt;
    const float xv = (float)xin[ml * DI + d];
    float u = cbv + w0 * cw4[0] + w1 * cw4[1] + w2 * cw4[2] + xv * cw4[3];
    u = u / (1.f + __expf(-u));
    w0 = w1; w1 = w2; w2 = xv;
    const float dtv = (float)dtb[ml * DI + d];
    const float du = dtv * u;
    S += dtv;
    float p = 0.f;
    if (fast) {
      const float r = __expf(-dtv);
      float P = 1.f;
#pragma unroll
      for (int s = 0; s < DS; s++) {
        P *= r;
        h[s] = P * h[s] + du * Bs[tt][s];
        p += h[s] * Cs[tt][s];
      }
    } else {
#pragma unroll
      for (int s = 0; s < DS; s++) {
        h[s] = __expf(dtv * a[s]) * h[s] + du * Bs[tt][s];
        p += h[s] * Cs[tt][s];
      }
    }
    pl[ml * DI + d] = (_Float16)(p + u * Dv);
    cd[ml * DI + d] = (_Float16)S;     // overwrites dtb[ml,d] AFTER its read
  }
  const size_t base = ((size_t)(b * NC + c) * DS) * DI + d;
#pragma unroll
  for (int s = 0; s < DS; s++) HE[base + (size_t)s * DI] = h[s];
  SA[(size_t)(b * NC + c) * DI + d] = S;
}

// ---------------------------------------------------------------------------
// K6 scan finish (absorbs old p2+p3): per-block local carry prefix over
// chunks c' < c (reads HE/SA), then elementwise
//   y = (pl + sum_s C[s]*exp(a_s*cumdt)*hc[s]) * silu(z).
// No serial recurrence over h — fully parallel; 2 blocks/CU.
// ---------------------------------------------------------------------------
__global__ __launch_bounds__(256) void scan_fin(
    const _Float16* __restrict__ part, const _Float16* __restrict__ pl,
    const _Float16* __restrict__ cd, const _Float16* __restrict__ zbuf,
    const float* __restrict__ HE, const float* __restrict__ SA,
    const float* __restrict__ atab, const unsigned char* __restrict__ aflag,
    _Float16* __restrict__ y) {
  __shared__ float Cs[CL][DS];
  const int bi = blockIdx.x;
  const int dseg = bi & 7;
  const int c = (bi >> 3) & (NC - 1);
  const int b = bi >> 8;
  const int t = threadIdx.x;
  const int d = dseg * 256 + t;
  const int mlbase = b * LL + c * CL;

  for (int i = t; i < CL * DS; i += 256) {
    const int tt = i >> 4, s = i & 15;
    float sc = 0.f;
#pragma unroll
    for (int z = 0; z < 16; z++)
      sc += (float)part[((size_t)z * MR + mlbase + tt) * XDBL + DTR + DS + s];
    Cs[tt][s] = sc;
  }

  const bool fast = aflag[d] != 0;
  float a[DS];
  if (!fast) {
#pragma unroll
    for (int s = 0; s < DS; s++) a[s] = atab[(size_t)d * DS + s];
  }
  // carry prefix: hc = state at end of chunk c-1 (with all earlier carries)
  float hc[DS];
#pragma unroll
  for (int s = 0; s < DS; s++) hc[s] = 0.f;
  for (int cc = 0; cc < c; cc++) {
    const float Sv = SA[(size_t)(b * NC + cc) * DI + d];
    const size_t hbase = ((size_t)(b * NC + cc) * DS) * DI + d;
    if (fast) {
      const float r = __expf(-Sv);
      float P = 1.f;
#pragma unroll
      for (int s = 0; s < DS; s++) {
        P *= r;
        hc[s] = P * hc[s] + HE[hbase + (size_t)s * DI];
      }
    } else {
#pragma unroll
      for (int s = 0; s < DS; s++)
        hc[s] = __expf(a[s] * Sv) * hc[s] + HE[hbase + (size_t)s * DI];
    }
  }
  __syncthreads();

  for (int tt = 0; tt < CL; tt++) {
    const size_t ml = mlbase + tt;
    const float cum = (float)cd[ml * DI + d];
    float acc = (float)pl[ml * DI + d];
    if (fast) {
      const float q = __expf(-cum);
      float Q = 1.f;
#pragma unroll
      for (int s = 0; s < DS; s++) {
        Q *= q;
        acc += Q * hc[s] * Cs[tt][s];
      }
    } else {
#pragma unroll
      for (int s = 0; s < DS; s++)
        acc += __expf(a[s] * cum) * hc[s] * Cs[tt][s];
    }
    const float zv = (float)zbuf[ml * DI + d];
    const float sil = zv / (1.f + __expf(-zv));
    y[ml * DI + d] = (_Float16)(acc * sil);
  }
}

// ---------------------------------------------------------------------------
// Launch: 7 dispatches (was 11). conv, xproj_reduce, scan_p2, out_reduce all
// deleted; their work folded into neighbors (no cross-dep fusion, no atomics).
// ---------------------------------------------------------------------------
extern "C" void kernel_launch(void* const* d_in, const int* in_sizes, int n_in,
                              void* d_out, int out_size, void* d_ws, size_t ws_size,
                              hipStream_t stream) {
  const float* x         = (const float*)d_in[0];
  const float* ln_w      = (const float*)d_in[1];
  const float* ln_b      = (const float*)d_in[2];
  const float* in_proj_w = (const float*)d_in[3];   // (4096, 1024)
  const float* conv_w    = (const float*)d_in[4];   // (2048, 1, 4)
  const float* conv_b    = (const float*)d_in[5];
  const float* x_proj_w  = (const float*)d_in[6];   // (96, 2048)
  const float* dt_proj_w = (const float*)d_in[7];   // (2048, 64)
  const float* dt_proj_b = (const float*)d_in[8];
  const float* A_log     = (const float*)d_in[9];   // (2048, 16)
  const float* Dvec      = (const float*)d_in[10];
  const float* out_proj_w= (const float*)d_in[11];  // (1024, 2048)
  float* out = (float*)d_out;

  // workspace (~72 MB extent, same as verified prior layouts). Aliasing:
  //   y aliases xin  (xin read through K5; y written K6, read K7)
  //   cd aliases dtb (dtb read-then-overwritten per-element in K5)
  char* ws = (char*)d_ws;
  _Float16* h_h      = (_Float16*)ws;                 //  4 MB  K1->K2
  _Float16* xin_h    = (_Float16*)(ws + 4194304);     //  8 MB  K2->K3,K5
  _Float16* y_h      = xin_h;                         //        K6->K7
  _Float16* z_h      = (_Float16*)(ws + 12582912);    //  8 MB  K2->K6
  _Float16* pl_h     = (_Float16*)(ws + 20971520);    //  8 MB  K5->K6
  _Float16* dtb_h    = (_Float16*)(ws + 29360128);    //  8 MB  K4->K5
  _Float16* cd_h     = dtb_h;                         //        K5->K6
  float*    SA       = (float*)   (ws + 46923776);    //  0.5 MB
  float*    atab     = (float*)   (ws + 47448064);    //  128 KB
  unsigned char* aflag = (unsigned char*)(ws + 47579136); // 2 KB
  float*    HE       = (float*)   (ws + 47710208);    //  8 MB  K5->K6
  _Float16* w_in_h   = (_Float16*)(ws + 56098816);    //  8 MB
  _Float16* w_out_h  = (_Float16*)(ws + 64487424);    //  4 MB
  _Float16* w_xp_h   = (_Float16*)(ws + 68681728);    //  0.375 MB
  _Float16* w_dt_h   = (_Float16*)(ws + 69074944);    //  0.25 MB
  _Float16* xp_part  = (_Float16*)(ws + 69337088);    //  6 MB  K3->K4,K5,K6

  // K1: layernorm + weight f2h + A-table
  front_kernel<<<MR + 6464 + 8, 256, 0, stream>>>(
      x, ln_w, ln_b, in_proj_w, out_proj_w, x_proj_w, dt_proj_w, A_log,
      h_h, w_in_h, w_out_h, w_xp_h, w_dt_h, atab, aflag);

  // K2: in_proj GEMM, N=4096, deep-pipelined, 512 blocks
  gemm_mfma<0, 128><<<dim3(2 * DI / 128, MR / 128, 1), 256, 0, stream>>>(
      h_h, w_in_h, xin_h, z_h, 0, MR, 2 * DI, DM, DM);

  // K3: x_proj GEMM with inline conv+silu A-staging, split-K 16, f16 partials
  xproj_conv<<<dim3(1, MR / 128, 16), 256, 0, stream>>>(
      xin_h, w_xp_h, conv_w, conv_b, xp_part);

  // K4: dt GEMM, A = sum of partials (cols<64), softplus -> dtb
  dt_kernel<<<dim3(DI / 64, MR / 128), 256, 0, stream>>>(
      xp_part, w_dt_h, dt_proj_b, dtb_h);

  // K5: scan phase 1 (inline conv; emits HE, SA, pl, cd)
  scan_p1<<<NB * NC * (DI / 256), 256, 0, stream>>>(
      xin_h, xp_part, dtb_h, atab, aflag, conv_w, conv_b, Dvec,
      HE, SA, pl_h, cd_h);

  // K6: scan finish (local carry prefix + elementwise y)
  scan_fin<<<NB * NC * (DI / 256), 256, 0, stream>>>(
      xp_part, pl_h, cd_h, z_h, HE, SA, atab, aflag, y_h);

  // K7: out_proj single-pass K=2048 + fused residual (out = x + y @ W^T)
  gemm_mfma<7, 128><<<dim3(DM / 128, MR / 128, 1), 256, 0, stream>>>(
      y_h, w_out_h, out, (void*)x, DM, MR, DM, DI, DI);
}

// Round 8
// 228.008 us; speedup vs baseline: 1.3319x; 1.3319x over previous
//
#include <hip/hip_runtime.h>
#include <hip/hip_bf16.h>
#include <math.h>

// Problem constants (from reference)
#define DM   1024        // d_model
#define DI   2048        // d_inner
#define DS   16          // d_state
#define DTR  64          // dt_rank
#define NB   2           // batch
#define LL   1024        // seq len
#define MR   (NB*LL)     // 2048 rows (b*l flattened)
#define XDBL 96          // dt_rank + 2*d_state
#define NC   32          // scan chunks
#define CL   32          // chunk length (2 blocks/CU — R5 lesson: keep)

typedef _Float16 half8  __attribute__((ext_vector_type(8)));
typedef _Float16 half4v __attribute__((ext_vector_type(4)));
typedef float    floatx4 __attribute__((ext_vector_type(4)));

__device__ __forceinline__ void gload_lds16(const void* g, void* l) {
  __builtin_amdgcn_global_load_lds(
      (const __attribute__((address_space(1))) void*)g,
      (__attribute__((address_space(3))) void*)l, 16, 0, 0);
}

// ---------------------------------------------------------------------------
// K1 front: LN (blocks < MR) + weight f2h (next 6464) + A-table (last 8).
// R7 lesson: scans must consume the SAME f16-rounded xc as x_proj — R7's
// unrounded inline-conv u in the scans pushed absmax 0.031 -> 0.135. This
// round restores the R1-exact datapath; conv is deleted by materializing xc
// from xproj_conv's staging instead.
// ---------------------------------------------------------------------------
__global__ __launch_bounds__(256) void front_kernel(
    const float* __restrict__ x, const float* __restrict__ ln_w,
    const float* __restrict__ ln_b,
    const float* __restrict__ w_in, const float* __restrict__ w_out,
    const float* __restrict__ w_xp, const float* __restrict__ w_dt,
    const float* __restrict__ A_log,
    _Float16* __restrict__ h_h,
    _Float16* __restrict__ w_in_h, _Float16* __restrict__ w_out_h,
    _Float16* __restrict__ w_xp_h, _Float16* __restrict__ w_dt_h,
    float* __restrict__ atab, unsigned char* __restrict__ aflag) {
  const int blk = blockIdx.x;
  if (blk < MR) {
    __shared__ float sA[4], sB[4];
    const float* xr = x + (size_t)blk * DM;
    float s = 0.f, ss = 0.f;
    for (int i = threadIdx.x; i < DM; i += 256) {
      float v = xr[i];
      s += v; ss += v * v;
    }
    for (int o = 32; o > 0; o >>= 1) {
      s  += __shfl_down(s, o, 64);
      ss += __shfl_down(ss, o, 64);
    }
    const int wid = threadIdx.x >> 6, lid = threadIdx.x & 63;
    if (lid == 0) { sA[wid] = s; sB[wid] = ss; }
    __syncthreads();
    if (threadIdx.x == 0) {
      float S = sA[0] + sA[1] + sA[2] + sA[3];
      float SS = sB[0] + sB[1] + sB[2] + sB[3];
      float mu = S / DM;
      sA[0] = mu;
      sB[0] = rsqrtf(SS / DM - mu * mu + 1e-5f);
    }
    __syncthreads();
    const float mu = sA[0], rs = sB[0];
    for (int i = threadIdx.x; i < DM; i += 256)
      h_h[(size_t)blk * DM + i] = (_Float16)((xr[i] - mu) * rs * ln_w[i] + ln_b[i]);
    return;
  }
  if (blk >= MR + 6464) {                         // A-table blocks (8)
    const int d = (blk - (MR + 6464)) * 256 + threadIdx.x;
    if (d < DI) {
      bool fast = true;
#pragma unroll
      for (int s = 0; s < DS; s++) {
        const float a = -__expf(A_log[(size_t)d * DS + s]);
        atab[(size_t)d * DS + s] = a;
        fast = fast && (fabsf(a + (float)(s + 1)) < 1e-4f);
      }
      aflag[d] = fast ? 1 : 0;
    }
    return;
  }
  int i = (blk - MR) * 256 + threadIdx.x;
  const int N0 = 1048576, N1 = 524288, N2 = 49152, N3 = 32768;
  const float* s; _Float16* d; int off;
  if (i < N0)            { s = w_in;  d = w_in_h;  off = i; }
  else if (i < N0+N1)    { s = w_out; d = w_out_h; off = i - N0; }
  else if (i < N0+N1+N2) { s = w_xp;  d = w_xp_h;  off = i - N0 - N1; }
  else if (i < N0+N1+N2+N3) { s = w_dt; d = w_dt_h; off = i - N0 - N1 - N2; }
  else return;
  float4 v = ((const float4*)s)[off];
  half4v h = {(_Float16)v.x, (_Float16)v.y, (_Float16)v.z, (_Float16)v.w};
  ((half4v*)d)[off] = h;
}

// ---------------------------------------------------------------------------
// MFMA f16 GEMM — verified counted-vmcnt depth-3 pipeline (R13/R1).
// Tile 128 x TN; 4 LDS buffers of 32-wide slabs.
// EPI 0: dual f16 store (n<DI -> Cv else C2v, compact DI-wide rows)
// EPI 4: f16 partial store at Cv + blockIdx.z*M*ldc (split-K, no atomics)
// EPI 5: f16 store softplus(acc + extra[n])
// ---------------------------------------------------------------------------
template <int EPI, int TN>
__global__ __launch_bounds__(256) void gemm_mfma(
    const _Float16* __restrict__ A,   // [M][K]
    const _Float16* __restrict__ W,   // [N][K]
    void* __restrict__ Cv, void* __restrict__ C2v,
    const float* __restrict__ extra, int ldc,
    int M, int N, int K, int kchunk) {
  constexpr int NT = (TN + 31) / 32;
  constexpr int WSLOT = TN / 16;
  constexpr int LPS = 2 + (WSLOT >= 8 ? 2 : 1);
  __shared__ alignas(16) _Float16 As[4][4096];
  __shared__ alignas(16) _Float16 Ws[4][4096];
  const int t = threadIdx.x;
  const int wave = t >> 6, lane = t & 63;
  const int m0 = blockIdx.y * 128, n0 = blockIdx.x * TN;
  const int k_beg = blockIdx.z * kchunk;
  const int nk = kchunk / 32;
  const int wm = (wave >> 1) * 64, wn = (wave & 1) * (TN / 2);
  floatx4 acc[4][NT];
#pragma unroll
  for (int i = 0; i < 4; i++)
#pragma unroll
    for (int j = 0; j < NT; j++) acc[i][j] = {0.f, 0.f, 0.f, 0.f};

  const int fr = lane & 15;
  const int kc8 = lane >> 4;
  const int kp = (kc8 ^ ((fr >> 1) & 3)) * 8;   // XOR bank swizzle

  auto stage = [&](int buf, int k0) {
    for (int sl = wave; sl < 8; sl += 4) {
      const int idx = sl * 64 + lane;
      const int row = idx >> 2;
      const int kc = (idx & 3) ^ ((row >> 1) & 3);
      gload_lds16(A + (size_t)(m0 + row) * K + k0 + kc * 8, &As[buf][sl * 512]);
    }
    for (int sl = wave; sl < WSLOT; sl += 4) {
      const int idx = sl * 64 + lane;
      const int row = idx >> 2;
      const int kc = (idx & 3) ^ ((row >> 1) & 3);
      const int wrow = (n0 + row < N) ? row : 0;
      gload_lds16(W + (size_t)(n0 + wrow) * K + k0 + kc * 8, &Ws[buf][sl * 512]);
    }
  };

  const int npre = nk < 3 ? nk : 3;
  for (int p = 0; p < npre; p++) stage(p, k_beg + p * 32);

  for (int ki = 0; ki < nk; ki++) {
    const int rem = nk - 1 - ki;
    if (rem >= 2)
      asm volatile("s_waitcnt vmcnt(%0)" :: "n"(2 * LPS) : "memory");
    else if (rem == 1)
      asm volatile("s_waitcnt vmcnt(%0)" :: "n"(LPS) : "memory");
    else
      asm volatile("s_waitcnt vmcnt(0)" ::: "memory");
    __builtin_amdgcn_s_barrier();
    const int cur = ki & 3;
    half8 af[4], wf[NT];
#pragma unroll
    for (int i = 0; i < 4; i++)
      af[i] = *(const half8*)&As[cur][(wm + i * 16 + fr) * 32 + kp];
#pragma unroll
    for (int j = 0; j < NT; j++)
      wf[j] = *(const half8*)&Ws[cur][(wn + j * 16 + fr) * 32 + kp];
    __builtin_amdgcn_s_setprio(1);
#pragma unroll
    for (int i = 0; i < 4; i++)
#pragma unroll
      for (int j = 0; j < NT; j++)
        acc[i][j] = __builtin_amdgcn_mfma_f32_16x16x32_f16(af[i], wf[j], acc[i][j], 0, 0, 0);
    __builtin_amdgcn_s_setprio(0);
    if (ki + 3 < nk) stage((ki + 3) & 3, k_beg + (ki + 3) * 32);
  }

  // epilogue: C/D layout col = lane&15, row = (lane>>4)*4 + reg
  const int col = lane & 15, rowq = lane >> 4;
#pragma unroll
  for (int i = 0; i < 4; i++) {
#pragma unroll
    for (int j = 0; j < NT; j++) {
      const int n = n0 + wn + j * 16 + col;
      if (n < N) {
#pragma unroll
        for (int r = 0; r < 4; r++) {
          const int m = m0 + wm + i * 16 + rowq * 4 + r;
          float v = acc[i][j][r];
          if (EPI == 0) {
            if (n < DI) ((_Float16*)Cv )[(size_t)m * DI + n]      = (_Float16)v;
            else        ((_Float16*)C2v)[(size_t)m * DI + n - DI] = (_Float16)v;
          } else if (EPI == 4) {
            ((_Float16*)Cv)[((size_t)blockIdx.z * M + m) * ldc + n] = (_Float16)v;
          } else if (EPI == 5) {
            v += extra[n];
            v = (v > 20.f) ? v : __logf(1.f + __expf(v));
            ((_Float16*)Cv)[(size_t)m * ldc + n] = (_Float16)v;
          }
        }
      }
    }
  }
}

// ---------------------------------------------------------------------------
// K3 x_proj GEMM with inline conv+SiLU in the A-staging (R6-verified) that
// NOW ALSO MATERIALIZES xc (each (m,d) is staged exactly once across the
// (y,z) grid — XOR swizzle is a bijection per row). Scans then read the same
// f16 xc as R1 -> bit-identical downstream numerics. Conv kernel deleted.
// ---------------------------------------------------------------------------
__global__ __launch_bounds__(256) void xproj_conv(
    const _Float16* __restrict__ xin, const _Float16* __restrict__ W,
    const float* __restrict__ cw, const float* __restrict__ cb,
    _Float16* __restrict__ part, _Float16* __restrict__ xc) {
  __shared__ alignas(16) _Float16 As[4][4096];   // 4 slabs x 128x32
  __shared__ alignas(16) _Float16 Ws[4][3072];   // 4 slabs x 96x32
  const int t = threadIdx.x, wave = t >> 6, lane = t & 63;
  const int m0 = blockIdx.y * 128;
  const int k0 = blockIdx.z * 128;
  for (int q = t; q < 2048; q += 256) {
    const int ss = q >> 9, idx = q & 511;
    const int row = idx >> 2;
    const int kc = (idx & 3) ^ ((row >> 1) & 3);
    const int m = m0 + row;
    const int l = m & (LL - 1);
    const int dbase = k0 + ss * 32 + kc * 8;
    float accv[8];
#pragma unroll
    for (int j = 0; j < 8; j++) accv[j] = cb[dbase + j];
#pragma unroll
    for (int k = 0; k < 4; k++) {
      const int lp = l - 3 + k;
      if (lp >= 0) {
        half8 xv = *(const half8*)&xin[(size_t)(m - 3 + k) * DI + dbase];
#pragma unroll
        for (int j = 0; j < 8; j++)
          accv[j] += (float)xv[j] * cw[(dbase + j) * 4 + k];
      }
    }
    half8 o;
#pragma unroll
    for (int j = 0; j < 8; j++)
      o[j] = (_Float16)(accv[j] / (1.f + __expf(-accv[j])));
    *(half8*)&As[ss][idx * 8] = o;
    *(half8*)&xc[(size_t)m * DI + dbase] = o;   // materialize xc (R1 values)
  }
  for (int q = wave; q < 24; q += 4) {
    const int ss = q / 6, sw = q % 6;
    const int idx = sw * 64 + lane;
    const int row = idx >> 2;
    const int kc = (idx & 3) ^ ((row >> 1) & 3);
    gload_lds16(W + (size_t)row * DI + k0 + ss * 32 + kc * 8, &Ws[ss][sw * 512]);
  }
  asm volatile("s_waitcnt vmcnt(0)" ::: "memory");
  __syncthreads();
  const int fr = lane & 15, kc8 = lane >> 4;
  const int kp = (kc8 ^ ((fr >> 1) & 3)) * 8;
  const int wm = (wave >> 1) * 64, wn = (wave & 1) * 48;
  floatx4 acc[4][3];
#pragma unroll
  for (int i = 0; i < 4; i++)
#pragma unroll
    for (int j = 0; j < 3; j++) acc[i][j] = {0.f, 0.f, 0.f, 0.f};
#pragma unroll
  for (int ss = 0; ss < 4; ss++) {
    half8 af[4], wf[3];
#pragma unroll
    for (int i = 0; i < 4; i++)
      af[i] = *(const half8*)&As[ss][(wm + i * 16 + fr) * 32 + kp];
#pragma unroll
    for (int j = 0; j < 3; j++)
      wf[j] = *(const half8*)&Ws[ss][(wn + j * 16 + fr) * 32 + kp];
#pragma unroll
    for (int i = 0; i < 4; i++)
#pragma unroll
      for (int j = 0; j < 3; j++)
        acc[i][j] = __builtin_amdgcn_mfma_f32_16x16x32_f16(af[i], wf[j], acc[i][j], 0, 0, 0);
  }
  const int col = lane & 15, rowq = lane >> 4;
#pragma unroll
  for (int i = 0; i < 4; i++) {
#pragma unroll
    for (int j = 0; j < 3; j++) {
      const int n = wn + j * 16 + col;
#pragma unroll
      for (int r = 0; r < 4; r++) {
        const int m = m0 + wm + i * 16 + rowq * 4 + r;
        part[((size_t)blockIdx.z * MR + m) * XDBL + n] = (_Float16)acc[i][j][r];
      }
    }
  }
}

// ---------------------------------------------------------------------------
// K4 x_proj partial reduce (R1-exact): x_dbl = sum_z part[z], emit dtr f16.
// ---------------------------------------------------------------------------
__global__ __launch_bounds__(256) void xproj_reduce(
    const _Float16* __restrict__ part,   // [16][MR][XDBL] f16
    float* __restrict__ x_dbl, _Float16* __restrict__ dtr) {
  const int idx = blockIdx.x * 256 + threadIdx.x;   // MR*XDBL = 196608
  const int m = idx / XDBL, c = idx - m * XDBL;
  float s = 0.f;
#pragma unroll
  for (int z = 0; z < 16; z++) s += (float)part[(size_t)z * (MR * XDBL) + idx];
  x_dbl[idx] = s;
  if (c < DTR) dtr[m * DTR + c] = (_Float16)s;
}

// ---------------------------------------------------------------------------
// out_proj partial reduce + residual (R1-exact): out = x + sum of 4 partials.
// ---------------------------------------------------------------------------
__global__ __launch_bounds__(256) void out_reduce(
    const float* __restrict__ x, const _Float16* __restrict__ part,  // [4][MR][DM]
    float* __restrict__ out) {
  const int i = blockIdx.x * 256 + threadIdx.x;   // MR*DM/4 = 524288
  float4 a = ((const float4*)x)[i];
#pragma unroll
  for (int z = 0; z < 4; z++) {
    half4v p = ((const half4v*)(part + (size_t)z * MR * DM))[i];
    a.x += (float)p.x; a.y += (float)p.y; a.z += (float)p.z; a.w += (float)p.w;
  }
  ((float4*)out)[i] = a;
}

// ---------------------------------------------------------------------------
// K6 scan phase 1 (R1-exact body; atab/aflag replace per-thread load_a).
// ---------------------------------------------------------------------------
__global__ __launch_bounds__(256) void scan_phase1(
    const _Float16* __restrict__ xc, const float* __restrict__ xdbl,
    const _Float16* __restrict__ dtm,
    const float* __restrict__ atab, const unsigned char* __restrict__ aflag,
    float* __restrict__ HE, float* __restrict__ SA) {
  __shared__ float Bs[CL][DS];
  const int bi = blockIdx.x;
  const int dblk = bi & 7;
  const int c = (bi >> 3) & (NC - 1);
  const int b = bi >> 8;
  const int t = threadIdx.x;
  const int d = dblk * 256 + t;
  const int mlbase = b * LL + c * CL;

  for (int i = t; i < CL * DS; i += 256) {
    int tt = i >> 4, s = i & 15;
    Bs[tt][s] = xdbl[(size_t)(mlbase + tt) * XDBL + DTR + s];
  }

  const bool fast = aflag[d] != 0;
  float a[DS];
  if (!fast) {
#pragma unroll
    for (int s = 0; s < DS; s++) a[s] = atab[(size_t)d * DS + s];
  }
  float h[DS];
#pragma unroll
  for (int s = 0; s < DS; s++) h[s] = 0.f;
  float S = 0.f;
  __syncthreads();

  if (fast) {
    for (int tt = 0; tt < CL; tt++) {
      const size_t ml = mlbase + tt;
      const float dtv = (float)dtm[ml * DI + d];
      const float u   = (float)xc[ml * DI + d];
      const float du  = dtv * u;
      S += dtv;
      const float r = __expf(-dtv);
      float P = 1.f;
#pragma unroll
      for (int s = 0; s < DS; s++) {
        P *= r;
        h[s] = P * h[s] + du * Bs[tt][s];
      }
    }
  } else {
    for (int tt = 0; tt < CL; tt++) {
      const size_t ml = mlbase + tt;
      const float dtv = (float)dtm[ml * DI + d];
      const float u   = (float)xc[ml * DI + d];
      const float du  = dtv * u;
      S += dtv;
#pragma unroll
      for (int s = 0; s < DS; s++)
        h[s] = __expf(dtv * a[s]) * h[s] + du * Bs[tt][s];
    }
  }
  const size_t base = ((size_t)(b * NC + c) * DS) * DI + d;
#pragma unroll
  for (int s = 0; s < DS; s++) HE[base + (size_t)s * DI] = h[s];
  SA[(size_t)(b * NC + c) * DI + d] = S;
}

// ---------------------------------------------------------------------------
// K7 scan phase 2 (R1-exact + atab): sequential combine; HE becomes carry-in.
// ---------------------------------------------------------------------------
__global__ __launch_bounds__(256) void scan_phase2(
    const float* __restrict__ atab,
    const float* __restrict__ SA,
    float* __restrict__ HE) {
  const int idx = blockIdx.x * 256 + threadIdx.x;  // NB*DS*DI
  const int d = idx & (DI - 1);
  const int s = (idx >> 11) & (DS - 1);
  const int b = idx >> 15;
  const float a = atab[(size_t)d * DS + s];
  float Hc = 0.f;
  for (int c = 0; c < NC; c++) {
    const size_t o = ((size_t)(b * NC + c) * DS + s) * DI + d;
    const float he = HE[o];
    const float P = __expf(a * SA[(size_t)(b * NC + c) * DI + d]);
    HE[o] = Hc;
    Hc = P * Hc + he;
  }
}

// ---------------------------------------------------------------------------
// K8 scan phase 3 (R1-exact body; atab/aflag): carry-in re-scan + fused y.
// ---------------------------------------------------------------------------
__global__ __launch_bounds__(256) void scan_phase3(
    const _Float16* __restrict__ xc, const float* __restrict__ xdbl,
    const _Float16* __restrict__ dtm, const _Float16* __restrict__ zbuf,
    const float* __restrict__ atab, const unsigned char* __restrict__ aflag,
    const float* __restrict__ Dvec, const float* __restrict__ HE,
    _Float16* __restrict__ y) {
  __shared__ float Bs[CL][DS];
  __shared__ float Cs[CL][DS];
  const int bi = blockIdx.x;
  const int dblk = bi & 7;
  const int c = (bi >> 3) & (NC - 1);
  const int b = bi >> 8;
  const int t = threadIdx.x;
  const int d = dblk * 256 + t;
  const int mlbase = b * LL + c * CL;

  for (int i = t; i < CL * DS; i += 256) {
    int tt = i >> 4, s = i & 15;
    const size_t ro = (size_t)(mlbase + tt) * XDBL + DTR + s;
    Bs[tt][s] = xdbl[ro];
    Cs[tt][s] = xdbl[ro + DS];
  }

  const bool fast = aflag[d] != 0;
  float a[DS];
  if (!fast) {
#pragma unroll
    for (int s = 0; s < DS; s++) a[s] = atab[(size_t)d * DS + s];
  }
  float h[DS];
  const size_t base = ((size_t)(b * NC + c) * DS) * DI + d;
#pragma unroll
  for (int s = 0; s < DS; s++) h[s] = HE[base + (size_t)s * DI];
  const float Dv = Dvec[d];
  __syncthreads();

  if (fast) {
    for (int tt = 0; tt < CL; tt++) {
      const size_t ml = mlbase + tt;
      const float dtv = (float)dtm[ml * DI + d];
      const float u   = (float)xc[ml * DI + d];
      const float du  = dtv * u;
      const float r = __expf(-dtv);
      float P = 1.f, p = 0.f;
#pragma unroll
      for (int s = 0; s < DS; s++) {
        P *= r;
        h[s] = P * h[s] + du * Bs[tt][s];
        p += h[s] * Cs[tt][s];
      }
      const float zv = (float)zbuf[ml * DI + d];
      const float sil = zv / (1.f + __expf(-zv));
      y[ml * DI + d] = (_Float16)((p + u * Dv) * sil);
    }
  } else {
    for (int tt = 0; tt < CL; tt++) {
      const size_t ml = mlbase + tt;
      const float dtv = (float)dtm[ml * DI + d];
      const float u   = (float)xc[ml * DI + d];
      const float du  = dtv * u;
      float p = 0.f;
#pragma unroll
      for (int s = 0; s < DS; s++) {
        h[s] = __expf(dtv * a[s]) * h[s] + du * Bs[tt][s];
        p += h[s] * Cs[tt][s];
      }
      const float zv = (float)zbuf[ml * DI + d];
      const float sil = zv / (1.f + __expf(-zv));
      y[ml * DI + d] = (_Float16)((p + u * Dv) * sil);
    }
  }
}

// ---------------------------------------------------------------------------
// Launch: 10 dispatches (R1 minus conv; xc materialized by xproj_conv).
// ---------------------------------------------------------------------------
extern "C" void kernel_launch(void* const* d_in, const int* in_sizes, int n_in,
                              void* d_out, int out_size, void* d_ws, size_t ws_size,
                              hipStream_t stream) {
  const float* x         = (const float*)d_in[0];
  const float* ln_w      = (const float*)d_in[1];
  const float* ln_b      = (const float*)d_in[2];
  const float* in_proj_w = (const float*)d_in[3];   // (4096, 1024)
  const float* conv_w    = (const float*)d_in[4];   // (2048, 1, 4)
  const float* conv_b    = (const float*)d_in[5];
  const float* x_proj_w  = (const float*)d_in[6];   // (96, 2048)
  const float* dt_proj_w = (const float*)d_in[7];   // (2048, 64)
  const float* dt_proj_b = (const float*)d_in[8];
  const float* A_log     = (const float*)d_in[9];   // (2048, 16)
  const float* Dvec      = (const float*)d_in[10];
  const float* out_proj_w= (const float*)d_in[11];  // (1024, 2048)
  float* out = (float*)d_out;

  // workspace layout (R1-proven offsets). Aliasing:
  //   y aliases xin (xin dead after K3 — scans read xc, not xin)
  //   out_part aliases dtb (dtb dead after K8)
  //   atab/aflag at dtb_end inside out_part (K1 write -> K6..K8 read -> K9
  //   overwrite; NO overlap with dtb itself)
  char* ws = (char*)d_ws;
  _Float16* h_h      = (_Float16*)ws;                 //  4 MB  K1->K2
  _Float16* xin_h    = (_Float16*)(ws + 4194304);     //  8 MB  K2->K3
  _Float16* y_h      = xin_h;                         //        K8->K9
  _Float16* z_h      = (_Float16*)(ws + 12582912);    //  8 MB  K2->K8
  _Float16* xc_h     = (_Float16*)(ws + 20971520);    //  8 MB  K3->K6,K8
  _Float16* dtb_h    = (_Float16*)(ws + 29360128);    //  8 MB  K5->K6,K8
  _Float16* out_part = dtb_h;                         // 16 MB  K9->K10
  float*    atab     = (float*)   (ws + 37748736);    //  128 KB K1->K8
  unsigned char* aflag = (unsigned char*)(ws + 37879808); // 2 KB
  float*    x_dbl    = (float*)   (ws + 46137344);    //  0.75 MB
  float*    SA       = (float*)   (ws + 46923776);    //  0.5 MB
  _Float16* dtr_h    = (_Float16*)(ws + 47448064);    //  0.25 MB
  float*    HE       = (float*)   (ws + 47710208);    //  8 MB
  _Float16* w_in_h   = (_Float16*)(ws + 56098816);    //  8 MB
  _Float16* w_out_h  = (_Float16*)(ws + 64487424);    //  4 MB
  _Float16* w_xp_h   = (_Float16*)(ws + 68681728);    //  0.375 MB
  _Float16* w_dt_h   = (_Float16*)(ws + 69074944);    //  0.25 MB
  _Float16* xp_part  = (_Float16*)(ws + 69337088);    //  6 MB  K3->K4

  // K1: layernorm + weight f2h + A-table
  front_kernel<<<MR + 6464 + 8, 256, 0, stream>>>(
      x, ln_w, ln_b, in_proj_w, out_proj_w, x_proj_w, dt_proj_w, A_log,
      h_h, w_in_h, w_out_h, w_xp_h, w_dt_h, atab, aflag);

  // K2: in_proj GEMM, N=4096, deep-pipelined, 512 blocks
  gemm_mfma<0, 128><<<dim3(2 * DI / 128, MR / 128, 1), 256, 0, stream>>>(
      h_h, w_in_h, xin_h, z_h, nullptr, 0, MR, 2 * DI, DM, DM);

  // K3: x_proj GEMM with inline conv+silu A-staging; materializes xc
  xproj_conv<<<dim3(1, MR / 128, 16), 256, 0, stream>>>(
      xin_h, w_xp_h, conv_w, conv_b, xp_part, xc_h);

  // K4: x_proj partial reduce -> f32 x_dbl + f16 dtr
  xproj_reduce<<<(MR * XDBL) / 256, 256, 0, stream>>>(xp_part, x_dbl, dtr_h);

  // K5: dt GEMM K=64 + fast softplus -> f16 dtb
  gemm_mfma<5, 64><<<dim3(DI / 64, MR / 128, 1), 256, 0, stream>>>(
      dtr_h, w_dt_h, dtb_h, nullptr, dt_proj_b, DI, MR, DI, DTR, DTR);

  // K6-K8: chunked selective scan (R1-exact, reads f16 xc)
  scan_phase1<<<NB * NC * (DI / 256), 256, 0, stream>>>(
      xc_h, x_dbl, dtb_h, atab, aflag, HE, SA);
  scan_phase2<<<(NB * DS * DI) / 256, 256, 0, stream>>>(atab, SA, HE);
  scan_phase3<<<NB * NC * (DI / 256), 256, 0, stream>>>(
      xc_h, x_dbl, dtb_h, z_h, atab, aflag, Dvec, HE, y_h);

  // K9: out_proj split-K 4 -> f16 partials
  gemm_mfma<4, 128><<<dim3(DM / 128, MR / 128, 4), 256, 0, stream>>>(
      y_h, w_out_h, out_part, nullptr, nullptr, DM, MR, DM, DI, DI / 4);

  // K10: residual + partial reduce
  out_reduce<<<(MR * DM / 4) / 256, 256, 0, stream>>>(x, out_part, out);
}